// Round 4
// baseline (310.606 us; speedup 1.0000x reference)
//
#include <hip/hip_runtime.h>
#include <hip/hip_bf16.h>

// GraphSAGE: 2x SAGEConv(mean) + linear head. N=40000, E=640000, D=128.
// Round 4: (a) gather reads bf16 feature rows (halves the dominant L2/L3
// traffic; self-path stays fp32 + bf16x3 MFMA for precision), (b) gather is
// fused into the conv (mean -> swizzled LDS tile -> MFMA fragments, zero
// barriers: each wave owns its 16 rows), (c) conv2 fuses the linear head
// (out = relu(h2)@Wo + bo via shfl_xor reduce) so h2/out round-trips vanish.

#define DH 128

typedef __attribute__((ext_vector_type(8))) short bf16x8;
typedef __attribute__((ext_vector_type(4))) float f32x4;

__device__ __forceinline__ unsigned short f2bf_rne(float f) {
    unsigned int u = __float_as_uint(f);
    return (unsigned short)((u + 0x7FFFu + ((u >> 16) & 1u)) >> 16);
}
__device__ __forceinline__ float bf2f(unsigned short h) {
    return __uint_as_float(((unsigned int)h) << 16);
}
__device__ __forceinline__ float bflo(unsigned int u) {
    return __uint_as_float(u << 16);
}
__device__ __forceinline__ float bfhi(unsigned int u) {
    return __uint_as_float(u & 0xffff0000u);
}

// ---------------- CSR build ----------------

__global__ void deg_kernel(const int* __restrict__ dst, int* __restrict__ deg, int E) {
    int i = blockIdx.x * blockDim.x + threadIdx.x;
    if (i < E) atomicAdd(&deg[dst[i]], 1);
}

__global__ __launch_bounds__(256) void scan1_kernel(
    const int* __restrict__ deg, int* __restrict__ offs, int* __restrict__ bsum, int N)
{
    __shared__ int tmp[256];
    int tid = threadIdx.x;
    int i = blockIdx.x * 256 + tid;
    int v = (i < N) ? deg[i] : 0;
    tmp[tid] = v;
    __syncthreads();
    #pragma unroll
    for (int off = 1; off < 256; off <<= 1) {
        int t = (tid >= off) ? tmp[tid - off] : 0;
        __syncthreads();
        tmp[tid] += t;
        __syncthreads();
    }
    if (i < N) offs[i] = tmp[tid] - v;
    if (tid == 255) bsum[blockIdx.x] = tmp[255];
}

__global__ __launch_bounds__(256) void scan2_kernel(
    const int* __restrict__ bsum, int* __restrict__ boffs, int nb)
{
    __shared__ int tmp[256];
    int tid = threadIdx.x;
    int v = (tid < nb) ? bsum[tid] : 0;
    tmp[tid] = v;
    __syncthreads();
    #pragma unroll
    for (int off = 1; off < 256; off <<= 1) {
        int t = (tid >= off) ? tmp[tid - off] : 0;
        __syncthreads();
        tmp[tid] += t;
        __syncthreads();
    }
    if (tid < nb) boffs[tid] = tmp[tid] - v;
}

__global__ void fill_kernel(const int* __restrict__ src, const int* __restrict__ dst,
                            const int* __restrict__ offs, const int* __restrict__ boffs,
                            int* __restrict__ cursor, int* __restrict__ csr, int E)
{
    int e = blockIdx.x * blockDim.x + threadIdx.x;
    if (e >= E) return;
    int d = dst[e];
    int pos = atomicAdd(&cursor[d], 1);
    csr[offs[d] + boffs[d >> 8] + pos] = src[e];
}

// ---------------- fp32 -> bf16 rows ----------------

__global__ __launch_bounds__(256) void tobf_kernel(
    const float* __restrict__ in, unsigned short* __restrict__ out, int n4)
{
    int i = blockIdx.x * 256 + threadIdx.x;
    if (i >= n4) return;
    float4 v = ((const float4*)in)[i];
    ushort4 o;
    o.x = f2bf_rne(v.x); o.y = f2bf_rne(v.y);
    o.z = f2bf_rne(v.z); o.w = f2bf_rne(v.w);
    ((ushort4*)out)[i] = o;
}

// ---------------- W pre-split: fragment-ready bf16 hi/lo ----------------
// B = [Wl ; Wr] (256x128). lane l supplies B[k = t*32 + (l>>4)*8 + j][col =
// f*16 + (l&15)], stored hi/lo[conv][t][f][lane][j] -> 16B/lane conv loads.

__global__ __launch_bounds__(256) void wprep_kernel(
    const float* __restrict__ W1l, const float* __restrict__ W1r,
    const float* __restrict__ W2l, const float* __restrict__ W2r,
    unsigned short* __restrict__ whi, unsigned short* __restrict__ wlo)
{
    int tid = blockIdx.x * 256 + threadIdx.x;       // [conv][t][f][lane]
    if (tid >= 2 * 8 * 8 * 64) return;
    int lane = tid & 63;
    int f = (tid >> 6) & 7;
    int t = (tid >> 9) & 7;
    int conv = tid >> 12;
    const float* Wl = conv ? W2l : W1l;
    const float* Wr = conv ? W2r : W1r;
    int c = f * 16 + (lane & 15);
    int kb = t * 32 + (lane >> 4) * 8;
    size_t off = (size_t)tid * 8;
    #pragma unroll
    for (int j = 0; j < 8; ++j) {
        int k = kb + j;
        float w = (k < 128) ? Wl[k * 128 + c] : Wr[(k - 128) * 128 + c];
        unsigned short h = f2bf_rne(w);
        whi[off + j] = h;
        wlo[off + j] = f2bf_rne(w - bf2f(h));
    }
}

// ---------------- fused SAGE conv: gather-mean -> LDS -> bf16x3 MFMA --------
// HEAD==0: H = relu([mean|X]@[Wl;Wr]+b) -> Hf (fp32) + Hbf (bf16 rows).
// HEAD==1: out = relu(...)@Wo + bo (no H materialization).
// 4 waves/block, 16 rows/wave, no barriers (wave-private LDS quadrants).

template<int HEAD>
__global__ __launch_bounds__(256) void sage_fused_kernel(
    const unsigned short* __restrict__ featbf, const float* __restrict__ Xself,
    const int* __restrict__ csr, const int* __restrict__ offs,
    const int* __restrict__ boffs, const int* __restrict__ deg,
    const unsigned short* __restrict__ whi, const unsigned short* __restrict__ wlo,
    const float* __restrict__ bias,
    float* __restrict__ Hf, unsigned short* __restrict__ Hbf,
    const float* __restrict__ Wo, const float* __restrict__ bo,
    float* __restrict__ outp)
{
    __shared__ float4 lds4[64 * 32];        // 32 KB agg tile, XOR-swizzled
    const int l = threadIdx.x & 63;
    const int wv = threadIdx.x >> 6;
    const int wrow0 = blockIdx.x * 64 + wv * 16;

    // ---- gather phase: mean over neighbors (bf16 rows), fp32 accumulate ----
    {
        const int half = l >> 5;
        const int c = l & 31;               // float4-slot within row
        for (int rr = 0; rr < 16; ++rr) {
            int node = wrow0 + rr;
            int dg = deg[node];
            int start = offs[node] + boffs[node >> 8];
            int end = start + dg;
            float4 a0 = make_float4(0.f, 0.f, 0.f, 0.f);
            float4 a1 = make_float4(0.f, 0.f, 0.f, 0.f);
            int e = start + half;
            for (; e + 2 < end; e += 4) {
                int s0 = csr[e], s1 = csr[e + 2];
                uint2 v0 = *(const uint2*)&featbf[(size_t)s0 * DH + c * 4];
                uint2 v1 = *(const uint2*)&featbf[(size_t)s1 * DH + c * 4];
                a0.x += bflo(v0.x); a0.y += bfhi(v0.x);
                a0.z += bflo(v0.y); a0.w += bfhi(v0.y);
                a1.x += bflo(v1.x); a1.y += bfhi(v1.x);
                a1.z += bflo(v1.y); a1.w += bfhi(v1.y);
            }
            if (e < end) {
                uint2 v0 = *(const uint2*)&featbf[(size_t)csr[e] * DH + c * 4];
                a0.x += bflo(v0.x); a0.y += bfhi(v0.x);
                a0.z += bflo(v0.y); a0.w += bfhi(v0.y);
            }
            a0.x += a1.x; a0.y += a1.y; a0.z += a1.z; a0.w += a1.w;
            a0.x += __shfl_down(a0.x, 32);
            a0.y += __shfl_down(a0.y, 32);
            a0.z += __shfl_down(a0.z, 32);
            a0.w += __shfl_down(a0.w, 32);
            if (half == 0) {
                float sc = 1.0f / (float)max(dg, 1);
                a0.x *= sc; a0.y *= sc; a0.z *= sc; a0.w *= sc;
                lds4[(wv * 16 + rr) * 32 + (c ^ (rr & 7))] = a0;
            }
        }
    }
    // no __syncthreads(): each wave reads only its own 16 LDS rows

    const int r = l & 15;
    const int kq = l >> 4;

    f32x4 acc[8];
    #pragma unroll
    for (int f = 0; f < 8; ++f) {
        float b = bias[f * 16 + r];
        acc[f] = (f32x4){b, b, b, b};
    }

    #pragma unroll
    for (int t = 0; t < 8; ++t) {
        float a[8];
        if (t < 4) {
            int fb = t * 8 + kq * 2;
            float4 f0 = lds4[(wv * 16 + r) * 32 + (fb ^ (r & 7))];
            float4 f1 = lds4[(wv * 16 + r) * 32 + ((fb + 1) ^ (r & 7))];
            a[0] = f0.x; a[1] = f0.y; a[2] = f0.z; a[3] = f0.w;
            a[4] = f1.x; a[5] = f1.y; a[6] = f1.z; a[7] = f1.w;
        } else {
            const float* ap = &Xself[(size_t)(wrow0 + r) * DH + (t & 3) * 32 + kq * 8];
            float4 f0 = *(const float4*)ap;
            float4 f1 = *(const float4*)(ap + 4);
            a[0] = f0.x; a[1] = f0.y; a[2] = f0.z; a[3] = f0.w;
            a[4] = f1.x; a[5] = f1.y; a[6] = f1.z; a[7] = f1.w;
        }
        bf16x8 ahi, alo;
        #pragma unroll
        for (int j = 0; j < 8; ++j) {
            unsigned short h = f2bf_rne(a[j]);
            ahi[j] = (short)h;
            alo[j] = (short)f2bf_rne(a[j] - bf2f(h));
        }
        const unsigned short* bh = whi + ((size_t)(t * 8) * 64 + l) * 8;
        const unsigned short* bl = wlo + ((size_t)(t * 8) * 64 + l) * 8;
        #pragma unroll
        for (int f = 0; f < 8; ++f) {
            bf16x8 bhi = *(const bf16x8*)(bh + (size_t)f * 64 * 8);
            bf16x8 blo = *(const bf16x8*)(bl + (size_t)f * 64 * 8);
            acc[f] = __builtin_amdgcn_mfma_f32_16x16x32_bf16(ahi, bhi, acc[f], 0, 0, 0);
            acc[f] = __builtin_amdgcn_mfma_f32_16x16x32_bf16(alo, bhi, acc[f], 0, 0, 0);
            acc[f] = __builtin_amdgcn_mfma_f32_16x16x32_bf16(ahi, blo, acc[f], 0, 0, 0);
        }
    }

    if (HEAD == 0) {
        #pragma unroll
        for (int f = 0; f < 8; ++f) {
            int col = f * 16 + r;
            #pragma unroll
            for (int q = 0; q < 4; ++q) {
                int row = wrow0 + kq * 4 + q;
                float v = fmaxf(acc[f][q], 0.0f);
                Hf[(size_t)row * DH + col] = v;
                Hbf[(size_t)row * DH + col] = f2bf_rne(v);
            }
        }
    } else {
        float wo[8];
        #pragma unroll
        for (int f = 0; f < 8; ++f) wo[f] = Wo[f * 16 + r];
        float s[4] = {0.f, 0.f, 0.f, 0.f};
        #pragma unroll
        for (int f = 0; f < 8; ++f)
            #pragma unroll
            for (int q = 0; q < 4; ++q)
                s[q] += fmaxf(acc[f][q], 0.0f) * wo[f];
        #pragma unroll
        for (int m = 1; m < 16; m <<= 1) {
            s[0] += __shfl_xor(s[0], m);
            s[1] += __shfl_xor(s[1], m);
            s[2] += __shfl_xor(s[2], m);
            s[3] += __shfl_xor(s[3], m);
        }
        if (r < 4) outp[wrow0 + kq * 4 + r] = s[r] + bo[0];
    }
}

extern "C" void kernel_launch(void* const* d_in, const int* in_sizes, int n_in,
                              void* d_out, int out_size, void* d_ws, size_t ws_size,
                              hipStream_t stream) {
    const float* x   = (const float*)d_in[0];
    const int*   ei  = (const int*)d_in[1];
    const float* W1l = (const float*)d_in[2];
    const float* b1  = (const float*)d_in[3];
    const float* W1r = (const float*)d_in[4];
    const float* W2l = (const float*)d_in[5];
    const float* b2  = (const float*)d_in[6];
    const float* W2r = (const float*)d_in[7];
    const float* Wo  = (const float*)d_in[8];
    const float* bo  = (const float*)d_in[9];
    float* out = (float*)d_out;

    const int N = in_sizes[0] / DH;      // 40000
    const int E = in_sizes[1] / 2;       // 640000
    const int* src = ei;
    const int* dst = ei + E;
    const int nb = (N + 255) / 256;

    // workspace layout (16B-aligned chunks)
    float* h1 = (float*)d_ws;                            // N*128 fp32
    unsigned short* xbf  = (unsigned short*)(h1 + (size_t)N * DH);  // N*128 bf16
    unsigned short* h1bf = xbf + (size_t)N * DH;                    // N*128 bf16
    int* deg    = (int*)(h1bf + (size_t)N * DH);         // N
    int* offs   = deg + N;                               // N
    int* cursor = offs + N;                              // N
    int* bsum   = cursor + N;                            // 256
    int* boffs  = bsum + 256;                            // 256
    int* csr    = boffs + 256;                           // E
    unsigned short* whi = (unsigned short*)(csr + E);    // 2*32768
    unsigned short* wlo = whi + 2 * 32768;               // 2*32768

    // ---- CSR build + dtype prep ----
    hipMemsetAsync(deg, 0, (size_t)N * sizeof(int), stream);
    hipMemsetAsync(cursor, 0, (size_t)N * sizeof(int), stream);
    deg_kernel<<<(E + 255) / 256, 256, 0, stream>>>(dst, deg, E);
    tobf_kernel<<<(N * DH / 4 + 255) / 256, 256, 0, stream>>>(x, xbf, N * DH / 4);
    wprep_kernel<<<32, 256, 0, stream>>>(W1l, W1r, W2l, W2r, whi, wlo);
    scan1_kernel<<<nb, 256, 0, stream>>>(deg, offs, bsum, N);
    scan2_kernel<<<1, 256, 0, stream>>>(bsum, boffs, nb);
    fill_kernel<<<(E + 255) / 256, 256, 0, stream>>>(src, dst, offs, boffs, cursor, csr, E);

    // ---- layer 1 (writes h1 fp32 + h1bf) ----
    sage_fused_kernel<0><<<N / 64, 256, 0, stream>>>(
        xbf, x, csr, offs, boffs, deg, whi, wlo, b1, h1, h1bf,
        nullptr, nullptr, nullptr);

    // ---- layer 2 + head (writes out directly) ----
    sage_fused_kernel<1><<<N / 64, 256, 0, stream>>>(
        h1bf, h1, csr, offs, boffs, deg, whi + 32768, wlo + 32768, b2,
        nullptr, nullptr, Wo, bo, out);
}

// Round 5
// 259.610 us; speedup vs baseline: 1.1964x; 1.1964x over previous
//
#include <hip/hip_runtime.h>
#include <hip/hip_bf16.h>

// GraphSAGE: 2x SAGEConv(mean) + linear head. N=40000, E=640000, D=128.
// Round 5: un-fuse gather from conv (round-4 fusion collapsed TLP: 2500 waves
// couldn't hide gather latency; standalone gather runs 40000 waves). Keep:
// bf16 feature rows for the gather (halves traffic), bf16x3 MFMA conv
// (LDS-free, barrier-free), fused linear head in conv2.

#define DH 128

typedef __attribute__((ext_vector_type(8))) short bf16x8;
typedef __attribute__((ext_vector_type(4))) float f32x4;

__device__ __forceinline__ unsigned short f2bf_rne(float f) {
    unsigned int u = __float_as_uint(f);
    return (unsigned short)((u + 0x7FFFu + ((u >> 16) & 1u)) >> 16);
}
__device__ __forceinline__ float bf2f(unsigned short h) {
    return __uint_as_float(((unsigned int)h) << 16);
}
__device__ __forceinline__ float bflo(unsigned int u) {
    return __uint_as_float(u << 16);
}
__device__ __forceinline__ float bfhi(unsigned int u) {
    return __uint_as_float(u & 0xffff0000u);
}

// ---------------- CSR build ----------------

__global__ void deg_kernel(const int* __restrict__ dst, int* __restrict__ deg, int E) {
    int i = blockIdx.x * blockDim.x + threadIdx.x;
    if (i < E) atomicAdd(&deg[dst[i]], 1);
}

__global__ __launch_bounds__(256) void scan1_kernel(
    const int* __restrict__ deg, int* __restrict__ offs, int* __restrict__ bsum, int N)
{
    __shared__ int tmp[256];
    int tid = threadIdx.x;
    int i = blockIdx.x * 256 + tid;
    int v = (i < N) ? deg[i] : 0;
    tmp[tid] = v;
    __syncthreads();
    #pragma unroll
    for (int off = 1; off < 256; off <<= 1) {
        int t = (tid >= off) ? tmp[tid - off] : 0;
        __syncthreads();
        tmp[tid] += t;
        __syncthreads();
    }
    if (i < N) offs[i] = tmp[tid] - v;
    if (tid == 255) bsum[blockIdx.x] = tmp[255];
}

__global__ __launch_bounds__(256) void scan2_kernel(
    const int* __restrict__ bsum, int* __restrict__ boffs, int nb)
{
    __shared__ int tmp[256];
    int tid = threadIdx.x;
    int v = (tid < nb) ? bsum[tid] : 0;
    tmp[tid] = v;
    __syncthreads();
    #pragma unroll
    for (int off = 1; off < 256; off <<= 1) {
        int t = (tid >= off) ? tmp[tid - off] : 0;
        __syncthreads();
        tmp[tid] += t;
        __syncthreads();
    }
    if (tid < nb) boffs[tid] = tmp[tid] - v;
}

__global__ void fill_kernel(const int* __restrict__ src, const int* __restrict__ dst,
                            const int* __restrict__ offs, const int* __restrict__ boffs,
                            int* __restrict__ cursor, int* __restrict__ csr, int E)
{
    int e = blockIdx.x * blockDim.x + threadIdx.x;
    if (e >= E) return;
    int d = dst[e];
    int pos = atomicAdd(&cursor[d], 1);
    csr[offs[d] + boffs[d >> 8] + pos] = src[e];
}

// ---------------- fp32 -> bf16 rows ----------------

__global__ __launch_bounds__(256) void tobf_kernel(
    const float* __restrict__ in, unsigned short* __restrict__ out, int n4)
{
    int i = blockIdx.x * 256 + threadIdx.x;
    if (i >= n4) return;
    float4 v = ((const float4*)in)[i];
    ushort4 o;
    o.x = f2bf_rne(v.x); o.y = f2bf_rne(v.y);
    o.z = f2bf_rne(v.z); o.w = f2bf_rne(v.w);
    ((ushort4*)out)[i] = o;
}

// ---------------- W pre-split: fragment-ready bf16 hi/lo ----------------
// B = [Wl ; Wr] (256x128). lane l supplies B[k = t*32 + (l>>4)*8 + j][col =
// f*16 + (l&15)], stored hi/lo[conv][t][f][lane][j] -> 16B/lane conv loads.

__global__ __launch_bounds__(256) void wprep_kernel(
    const float* __restrict__ W1l, const float* __restrict__ W1r,
    const float* __restrict__ W2l, const float* __restrict__ W2r,
    unsigned short* __restrict__ whi, unsigned short* __restrict__ wlo)
{
    int tid = blockIdx.x * 256 + threadIdx.x;       // [conv][t][f][lane]
    if (tid >= 2 * 8 * 8 * 64) return;
    int lane = tid & 63;
    int f = (tid >> 6) & 7;
    int t = (tid >> 9) & 7;
    int conv = tid >> 12;
    const float* Wl = conv ? W2l : W1l;
    const float* Wr = conv ? W2r : W1r;
    int c = f * 16 + (lane & 15);
    int kb = t * 32 + (lane >> 4) * 8;
    size_t off = (size_t)tid * 8;
    #pragma unroll
    for (int j = 0; j < 8; ++j) {
        int k = kb + j;
        float w = (k < 128) ? Wl[k * 128 + c] : Wr[(k - 128) * 128 + c];
        unsigned short h = f2bf_rne(w);
        whi[off + j] = h;
        wlo[off + j] = f2bf_rne(w - bf2f(h));
    }
}

// ------------- gather mean over bf16 rows (one wave per node) -------------
// 32 lanes cover the 256B bf16 row as uint2 (4 bf16 each); the two 32-lane
// halves take alternate edges; 2-deep unroll per half. fp32 accumulate,
// fp32 mean written to Agg.

__global__ __launch_bounds__(256) void gather_mean_kernel(
    const unsigned short* __restrict__ featbf, const int* __restrict__ csr,
    const int* __restrict__ offs, const int* __restrict__ boffs,
    const int* __restrict__ deg, float* __restrict__ out, int N)
{
    int node = blockIdx.x * 4 + (threadIdx.x >> 6);
    if (node >= N) return;
    int lane = threadIdx.x & 63;
    int c = lane & 31;
    int half = lane >> 5;

    int start = offs[node] + boffs[node >> 8];
    int dg = deg[node];
    int end = start + dg;

    float4 a0 = make_float4(0.f, 0.f, 0.f, 0.f);
    float4 a1 = make_float4(0.f, 0.f, 0.f, 0.f);
    int e = start + half;
    for (; e + 2 < end; e += 4) {
        int s0 = csr[e], s1 = csr[e + 2];
        uint2 v0 = *(const uint2*)&featbf[(size_t)s0 * DH + c * 4];
        uint2 v1 = *(const uint2*)&featbf[(size_t)s1 * DH + c * 4];
        a0.x += bflo(v0.x); a0.y += bfhi(v0.x);
        a0.z += bflo(v0.y); a0.w += bfhi(v0.y);
        a1.x += bflo(v1.x); a1.y += bfhi(v1.x);
        a1.z += bflo(v1.y); a1.w += bfhi(v1.y);
    }
    if (e < end) {
        uint2 v0 = *(const uint2*)&featbf[(size_t)csr[e] * DH + c * 4];
        a0.x += bflo(v0.x); a0.y += bfhi(v0.x);
        a0.z += bflo(v0.y); a0.w += bfhi(v0.y);
    }
    a0.x += a1.x; a0.y += a1.y; a0.z += a1.z; a0.w += a1.w;
    a0.x += __shfl_down(a0.x, 32);
    a0.y += __shfl_down(a0.y, 32);
    a0.z += __shfl_down(a0.z, 32);
    a0.w += __shfl_down(a0.w, 32);
    if (half == 0) {
        float sc = 1.0f / (float)max(dg, 1);
        a0.x *= sc; a0.y *= sc; a0.z *= sc; a0.w *= sc;
        *(float4*)&out[(size_t)node * DH + c * 4] = a0;
    }
}

// ---------------- SAGE conv via bf16x3 MFMA ----------------
// HEAD==0: Hf = relu([Agg|X]@[Wl;Wr]+b) fp32, plus Hbf bf16 rows.
// HEAD==1: out = relu(...)@Wo + bo (16-lane shfl_xor reduce).
// 4 waves/block, 16 rows/wave, no LDS, no barriers.

template<int HEAD>
__global__ __launch_bounds__(256) void sage_mfma_kernel(
    const float* __restrict__ Agg, const float* __restrict__ X,
    const unsigned short* __restrict__ whi, const unsigned short* __restrict__ wlo,
    const float* __restrict__ bias,
    float* __restrict__ Hf, unsigned short* __restrict__ Hbf,
    const float* __restrict__ Wo, const float* __restrict__ bo,
    float* __restrict__ outp)
{
    const int l = threadIdx.x & 63;
    const int wv = threadIdx.x >> 6;
    const int row0 = blockIdx.x * 64 + wv * 16;
    const int r = l & 15;
    const int kq = l >> 4;          // 0..3

    f32x4 acc[8];
    #pragma unroll
    for (int f = 0; f < 8; ++f) {
        float b = bias[f * 16 + r];
        acc[f] = (f32x4){b, b, b, b};
    }

    #pragma unroll
    for (int t = 0; t < 8; ++t) {
        const float* A = (t < 4) ? Agg : X;
        const float* ap = &A[(size_t)(row0 + r) * DH + (t & 3) * 32 + kq * 8];
        float4 f0 = *(const float4*)ap;
        float4 f1 = *(const float4*)(ap + 4);
        float a[8] = {f0.x, f0.y, f0.z, f0.w, f1.x, f1.y, f1.z, f1.w};
        bf16x8 ahi, alo;
        #pragma unroll
        for (int j = 0; j < 8; ++j) {
            unsigned short h = f2bf_rne(a[j]);
            ahi[j] = (short)h;
            alo[j] = (short)f2bf_rne(a[j] - bf2f(h));
        }
        const unsigned short* bh = whi + ((size_t)(t * 8) * 64 + l) * 8;
        const unsigned short* bl = wlo + ((size_t)(t * 8) * 64 + l) * 8;
        #pragma unroll
        for (int f = 0; f < 8; ++f) {
            bf16x8 bhi = *(const bf16x8*)(bh + (size_t)f * 64 * 8);
            bf16x8 blo = *(const bf16x8*)(bl + (size_t)f * 64 * 8);
            acc[f] = __builtin_amdgcn_mfma_f32_16x16x32_bf16(ahi, bhi, acc[f], 0, 0, 0);
            acc[f] = __builtin_amdgcn_mfma_f32_16x16x32_bf16(alo, bhi, acc[f], 0, 0, 0);
            acc[f] = __builtin_amdgcn_mfma_f32_16x16x32_bf16(ahi, blo, acc[f], 0, 0, 0);
        }
    }

    if (HEAD == 0) {
        #pragma unroll
        for (int f = 0; f < 8; ++f) {
            int col = f * 16 + r;
            #pragma unroll
            for (int q = 0; q < 4; ++q) {
                int row = row0 + kq * 4 + q;
                float v = fmaxf(acc[f][q], 0.0f);
                Hf[(size_t)row * DH + col] = v;
                Hbf[(size_t)row * DH + col] = f2bf_rne(v);
            }
        }
    } else {
        float wo[8];
        #pragma unroll
        for (int f = 0; f < 8; ++f) wo[f] = Wo[f * 16 + r];
        float s[4] = {0.f, 0.f, 0.f, 0.f};
        #pragma unroll
        for (int f = 0; f < 8; ++f)
            #pragma unroll
            for (int q = 0; q < 4; ++q)
                s[q] += fmaxf(acc[f][q], 0.0f) * wo[f];
        #pragma unroll
        for (int m = 1; m < 16; m <<= 1) {
            s[0] += __shfl_xor(s[0], m);
            s[1] += __shfl_xor(s[1], m);
            s[2] += __shfl_xor(s[2], m);
            s[3] += __shfl_xor(s[3], m);
        }
        if (r < 4) outp[row0 + kq * 4 + r] = s[r] + bo[0];
    }
}

extern "C" void kernel_launch(void* const* d_in, const int* in_sizes, int n_in,
                              void* d_out, int out_size, void* d_ws, size_t ws_size,
                              hipStream_t stream) {
    const float* x   = (const float*)d_in[0];
    const int*   ei  = (const int*)d_in[1];
    const float* W1l = (const float*)d_in[2];
    const float* b1  = (const float*)d_in[3];
    const float* W1r = (const float*)d_in[4];
    const float* W2l = (const float*)d_in[5];
    const float* b2  = (const float*)d_in[6];
    const float* W2r = (const float*)d_in[7];
    const float* Wo  = (const float*)d_in[8];
    const float* bo  = (const float*)d_in[9];
    float* out = (float*)d_out;

    const int N = in_sizes[0] / DH;      // 40000
    const int E = in_sizes[1] / 2;       // 640000
    const int* src = ei;
    const int* dst = ei + E;
    const int nb = (N + 255) / 256;

    // workspace layout (16B-aligned chunks)
    float* agg = (float*)d_ws;                           // N*128 fp32
    float* h1  = agg + (size_t)N * DH;                   // N*128 fp32
    unsigned short* xbf  = (unsigned short*)(h1 + (size_t)N * DH);  // N*128 bf16
    unsigned short* h1bf = xbf + (size_t)N * DH;                    // N*128 bf16
    int* deg    = (int*)(h1bf + (size_t)N * DH);         // N
    int* offs   = deg + N;                               // N
    int* cursor = offs + N;                              // N
    int* bsum   = cursor + N;                            // 256
    int* boffs  = bsum + 256;                            // 256
    int* csr    = boffs + 256;                           // E
    unsigned short* whi = (unsigned short*)(csr + E);    // 2*32768
    unsigned short* wlo = whi + 2 * 32768;               // 2*32768

    // ---- CSR build + dtype prep ----
    hipMemsetAsync(deg, 0, (size_t)N * sizeof(int), stream);
    hipMemsetAsync(cursor, 0, (size_t)N * sizeof(int), stream);
    deg_kernel<<<(E + 255) / 256, 256, 0, stream>>>(dst, deg, E);
    tobf_kernel<<<(N * DH / 4 + 255) / 256, 256, 0, stream>>>(x, xbf, N * DH / 4);
    wprep_kernel<<<32, 256, 0, stream>>>(W1l, W1r, W2l, W2r, whi, wlo);
    scan1_kernel<<<nb, 256, 0, stream>>>(deg, offs, bsum, N);
    scan2_kernel<<<1, 256, 0, stream>>>(bsum, boffs, nb);
    fill_kernel<<<(E + 255) / 256, 256, 0, stream>>>(src, dst, offs, boffs, cursor, csr, E);

    // ---- layer 1 ----
    gather_mean_kernel<<<(N + 3) / 4, 256, 0, stream>>>(xbf, csr, offs, boffs, deg, agg, N);
    sage_mfma_kernel<0><<<N / 64, 256, 0, stream>>>(
        agg, x, whi, wlo, b1, h1, h1bf, nullptr, nullptr, nullptr);

    // ---- layer 2 + head ----
    gather_mean_kernel<<<(N + 3) / 4, 256, 0, stream>>>(h1bf, csr, offs, boffs, deg, agg, N);
    sage_mfma_kernel<1><<<N / 64, 256, 0, stream>>>(
        agg, h1, whi + 32768, wlo + 32768, b2, nullptr, nullptr, Wo, bo, out);
}

// Round 6
// 257.963 us; speedup vs baseline: 1.2041x; 1.0064x over previous
//
#include <hip/hip_runtime.h>
#include <hip/hip_bf16.h>

// GraphSAGE: 2x SAGEConv(mean) + linear head. N=40000, E=640000, D=128.
// Round 6: conv was operand-prep-bound, not MFMA-bound. (a) all MFMA A-operands
// pre-split into bf16 hi/lo arrays (conversion moved into memory-bound
// kernels; conv has zero conversion VALU), (b) 32 rows/wave halves W-fragment
// L2 traffic, (c) gather 4-deep unroll for MLP, (d) prep fused into one
// kernel, single memset. Head stays fused into conv2.

#define DH 128

typedef __attribute__((ext_vector_type(8))) short bf16x8;
typedef __attribute__((ext_vector_type(4))) float f32x4;

__device__ __forceinline__ unsigned short f2bf_rne(float f) {
    unsigned int u = __float_as_uint(f);
    return (unsigned short)((u + 0x7FFFu + ((u >> 16) & 1u)) >> 16);
}
__device__ __forceinline__ float bf2f(unsigned short h) {
    return __uint_as_float(((unsigned int)h) << 16);
}
__device__ __forceinline__ float bflo(unsigned int u) {
    return __uint_as_float(u << 16);
}
__device__ __forceinline__ float bfhi(unsigned int u) {
    return __uint_as_float(u & 0xffff0000u);
}

// ---------------- fused prep: x->hi/lo, degree histogram, W pre-split -------
// Block roles: [0,nbA) fp32->bf16 hi/lo rows; [nbA,nbA+nbB) deg histogram;
// [nbA+nbB, +32) W fragment pre-split.
// xhi is RNE (consumed hi-only by gather1 -> must be unbiased); xlo = RNE(x-hi).

__global__ __launch_bounds__(256) void prep_kernel(
    const float* __restrict__ x,
    unsigned short* __restrict__ xhi, unsigned short* __restrict__ xlo,
    const int* __restrict__ dst, int* __restrict__ deg,
    const float* __restrict__ W1l, const float* __restrict__ W1r,
    const float* __restrict__ W2l, const float* __restrict__ W2r,
    unsigned short* __restrict__ whi, unsigned short* __restrict__ wlo,
    int n4, int E, int nbA, int nbB)
{
    int b = blockIdx.x;
    if (b < nbA) {
        int i = b * 256 + threadIdx.x;
        if (i >= n4) return;
        float4 v = ((const float4*)x)[i];
        unsigned short hx = f2bf_rne(v.x), hy = f2bf_rne(v.y);
        unsigned short hz = f2bf_rne(v.z), hw = f2bf_rne(v.w);
        uint2 hi, lo;
        hi.x = ((unsigned)hy << 16) | hx;
        hi.y = ((unsigned)hw << 16) | hz;
        lo.x = ((unsigned)f2bf_rne(v.y - bf2f(hy)) << 16) | f2bf_rne(v.x - bf2f(hx));
        lo.y = ((unsigned)f2bf_rne(v.w - bf2f(hw)) << 16) | f2bf_rne(v.z - bf2f(hz));
        ((uint2*)xhi)[i] = hi;
        ((uint2*)xlo)[i] = lo;
    } else if (b < nbA + nbB) {
        int i = (b - nbA) * 256 + threadIdx.x;
        if (i < E) atomicAdd(&deg[dst[i]], 1);
    } else {
        int tid = (b - nbA - nbB) * 256 + threadIdx.x;  // [conv][t][f][lane]
        if (tid >= 2 * 8 * 8 * 64) return;
        int lane = tid & 63;
        int f = (tid >> 6) & 7;
        int t = (tid >> 9) & 7;
        int conv = tid >> 12;
        const float* Wl = conv ? W2l : W1l;
        const float* Wr = conv ? W2r : W1r;
        int c = f * 16 + (lane & 15);
        int kb = t * 32 + (lane >> 4) * 8;
        size_t off = (size_t)tid * 8;
        #pragma unroll
        for (int j = 0; j < 8; ++j) {
            int k = kb + j;
            float w = (k < 128) ? Wl[k * 128 + c] : Wr[(k - 128) * 128 + c];
            unsigned short h = f2bf_rne(w);
            whi[off + j] = h;
            wlo[off + j] = f2bf_rne(w - bf2f(h));
        }
    }
}

// ---------------- CSR scans + fill ----------------

__global__ __launch_bounds__(256) void scan1_kernel(
    const int* __restrict__ deg, int* __restrict__ offs, int* __restrict__ bsum, int N)
{
    __shared__ int tmp[256];
    int tid = threadIdx.x;
    int i = blockIdx.x * 256 + tid;
    int v = (i < N) ? deg[i] : 0;
    tmp[tid] = v;
    __syncthreads();
    #pragma unroll
    for (int off = 1; off < 256; off <<= 1) {
        int t = (tid >= off) ? tmp[tid - off] : 0;
        __syncthreads();
        tmp[tid] += t;
        __syncthreads();
    }
    if (i < N) offs[i] = tmp[tid] - v;
    if (tid == 255) bsum[blockIdx.x] = tmp[255];
}

__global__ __launch_bounds__(256) void scan2_kernel(
    const int* __restrict__ bsum, int* __restrict__ boffs, int nb)
{
    __shared__ int tmp[256];
    int tid = threadIdx.x;
    int v = (tid < nb) ? bsum[tid] : 0;
    tmp[tid] = v;
    __syncthreads();
    #pragma unroll
    for (int off = 1; off < 256; off <<= 1) {
        int t = (tid >= off) ? tmp[tid - off] : 0;
        __syncthreads();
        tmp[tid] += t;
        __syncthreads();
    }
    if (tid < nb) boffs[tid] = tmp[tid] - v;
}

__global__ void fill_kernel(const int* __restrict__ src, const int* __restrict__ dst,
                            const int* __restrict__ offs, const int* __restrict__ boffs,
                            int* __restrict__ cursor, int* __restrict__ csr, int E)
{
    int e = blockIdx.x * blockDim.x + threadIdx.x;
    if (e >= E) return;
    int d = dst[e];
    int pos = atomicAdd(&cursor[d], 1);
    csr[offs[d] + boffs[d >> 8] + pos] = src[e];
}

// ------------- gather mean over bf16 rows (one wave per node) -------------
// 32 lanes cover the 256B row as uint2; halves take alternate edges; 4-deep
// unroll per half. fp32 accumulate; mean written as bf16 hi(trunc)/lo(RNE)
// pair (combined 2^-17 precision; consumed only as a pair by the conv).

__global__ __launch_bounds__(256) void gather_mean_kernel(
    const unsigned short* __restrict__ featbf, const int* __restrict__ csr,
    const int* __restrict__ offs, const int* __restrict__ boffs,
    const int* __restrict__ deg,
    unsigned short* __restrict__ outhi, unsigned short* __restrict__ outlo, int N)
{
    int node = blockIdx.x * 4 + (threadIdx.x >> 6);
    if (node >= N) return;
    int lane = threadIdx.x & 63;
    int c = lane & 31;
    int half = lane >> 5;

    int start = offs[node] + boffs[node >> 8];
    int dg = deg[node];
    int end = start + dg;

    float4 a0 = make_float4(0.f,0.f,0.f,0.f), a1 = a0, a2 = a0, a3 = a0;
    int e = start + half;
    for (; e + 6 < end; e += 8) {
        int s0 = csr[e], s1 = csr[e + 2], s2 = csr[e + 4], s3 = csr[e + 6];
        uint2 v0 = *(const uint2*)&featbf[(size_t)s0 * DH + c * 4];
        uint2 v1 = *(const uint2*)&featbf[(size_t)s1 * DH + c * 4];
        uint2 v2 = *(const uint2*)&featbf[(size_t)s2 * DH + c * 4];
        uint2 v3 = *(const uint2*)&featbf[(size_t)s3 * DH + c * 4];
        a0.x += bflo(v0.x); a0.y += bfhi(v0.x); a0.z += bflo(v0.y); a0.w += bfhi(v0.y);
        a1.x += bflo(v1.x); a1.y += bfhi(v1.x); a1.z += bflo(v1.y); a1.w += bfhi(v1.y);
        a2.x += bflo(v2.x); a2.y += bfhi(v2.x); a2.z += bflo(v2.y); a2.w += bfhi(v2.y);
        a3.x += bflo(v3.x); a3.y += bfhi(v3.x); a3.z += bflo(v3.y); a3.w += bfhi(v3.y);
    }
    for (; e < end; e += 2) {
        uint2 v = *(const uint2*)&featbf[(size_t)csr[e] * DH + c * 4];
        a0.x += bflo(v.x); a0.y += bfhi(v.x); a0.z += bflo(v.y); a0.w += bfhi(v.y);
    }
    a0.x += a1.x + a2.x + a3.x;
    a0.y += a1.y + a2.y + a3.y;
    a0.z += a1.z + a2.z + a3.z;
    a0.w += a1.w + a2.w + a3.w;
    a0.x += __shfl_down(a0.x, 32);
    a0.y += __shfl_down(a0.y, 32);
    a0.z += __shfl_down(a0.z, 32);
    a0.w += __shfl_down(a0.w, 32);
    if (half == 0) {
        float sc = 1.0f / (float)max(dg, 1);
        a0.x *= sc; a0.y *= sc; a0.z *= sc; a0.w *= sc;
        unsigned int ux = __float_as_uint(a0.x), uy = __float_as_uint(a0.y);
        unsigned int uz = __float_as_uint(a0.z), uw = __float_as_uint(a0.w);
        uint2 hi;
        hi.x = (uy & 0xffff0000u) | (ux >> 16);
        hi.y = (uw & 0xffff0000u) | (uz >> 16);
        uint2 lo;
        lo.x = ((unsigned)f2bf_rne(a0.y - __uint_as_float(uy & 0xffff0000u)) << 16)
             | f2bf_rne(a0.x - __uint_as_float(ux & 0xffff0000u));
        lo.y = ((unsigned)f2bf_rne(a0.w - __uint_as_float(uw & 0xffff0000u)) << 16)
             | f2bf_rne(a0.z - __uint_as_float(uz & 0xffff0000u));
        *(uint2*)&outhi[(size_t)node * DH + c * 4] = hi;
        *(uint2*)&outlo[(size_t)node * DH + c * 4] = lo;
    }
}

// ---------------- SAGE conv via bf16x3 MFMA, pre-split operands --------------
// HEAD==0: relu([Agg|X]@[Wl;Wr]+b) -> Hhi (RNE bf16, gather2 input) + Hlo.
// HEAD==1: out = relu(...)@Wo + bo (16-lane shfl_xor reduce).
// 4 waves/block, 32 rows/wave (2 row-groups 64 apart), no LDS, no barriers.

template<int HEAD>
__global__ __launch_bounds__(256) void sage_mfma_kernel(
    const unsigned short* __restrict__ agghi, const unsigned short* __restrict__ agglo,
    const unsigned short* __restrict__ xhi, const unsigned short* __restrict__ xlo,
    const unsigned short* __restrict__ whi, const unsigned short* __restrict__ wlo,
    const float* __restrict__ bias,
    unsigned short* __restrict__ Hhi, unsigned short* __restrict__ Hlo,
    const float* __restrict__ Wo, const float* __restrict__ bo,
    float* __restrict__ outp, int N)
{
    const int l = threadIdx.x & 63;
    const int wv = threadIdx.x >> 6;
    const int r = l & 15;
    const int kq = l >> 4;
    const int base0 = blockIdx.x * 128 + wv * 16;
    const int base1 = base0 + 64;
    const bool v1 = (base1 + 16 <= N);

    f32x4 acc0[8], acc1[8];
    #pragma unroll
    for (int f = 0; f < 8; ++f) {
        float b = bias[f * 16 + r];
        acc0[f] = (f32x4){b, b, b, b};
        acc1[f] = (f32x4){b, b, b, b};
    }

    #pragma unroll
    for (int t = 0; t < 8; ++t) {
        const unsigned short* Ah = (t < 4) ? agghi : xhi;
        const unsigned short* Al = (t < 4) ? agglo : xlo;
        size_t ao0 = (size_t)(base0 + r) * DH + (t & 3) * 32 + kq * 8;
        bf16x8 a0h = *(const bf16x8*)&Ah[ao0];
        bf16x8 a0l = *(const bf16x8*)&Al[ao0];
        bf16x8 a1h = {0,0,0,0,0,0,0,0};
        bf16x8 a1l = {0,0,0,0,0,0,0,0};
        if (v1) {
            size_t ao1 = ao0 + (size_t)64 * DH;
            a1h = *(const bf16x8*)&Ah[ao1];
            a1l = *(const bf16x8*)&Al[ao1];
        }
        const unsigned short* bh = whi + ((size_t)(t * 8) * 64 + l) * 8;
        const unsigned short* bl = wlo + ((size_t)(t * 8) * 64 + l) * 8;
        #pragma unroll
        for (int f = 0; f < 8; ++f) {
            bf16x8 bhi = *(const bf16x8*)(bh + (size_t)f * 512);
            bf16x8 blo = *(const bf16x8*)(bl + (size_t)f * 512);
            acc0[f] = __builtin_amdgcn_mfma_f32_16x16x32_bf16(a0h, bhi, acc0[f], 0, 0, 0);
            acc0[f] = __builtin_amdgcn_mfma_f32_16x16x32_bf16(a0l, bhi, acc0[f], 0, 0, 0);
            acc0[f] = __builtin_amdgcn_mfma_f32_16x16x32_bf16(a0h, blo, acc0[f], 0, 0, 0);
            acc1[f] = __builtin_amdgcn_mfma_f32_16x16x32_bf16(a1h, bhi, acc1[f], 0, 0, 0);
            acc1[f] = __builtin_amdgcn_mfma_f32_16x16x32_bf16(a1l, bhi, acc1[f], 0, 0, 0);
            acc1[f] = __builtin_amdgcn_mfma_f32_16x16x32_bf16(a1h, blo, acc1[f], 0, 0, 0);
        }
    }

    if (HEAD == 0) {
        #pragma unroll
        for (int rg = 0; rg < 2; ++rg) {
            if (rg == 1 && !v1) break;
            int base = rg ? base1 : base0;
            #pragma unroll
            for (int f = 0; f < 8; ++f) {
                int col = f * 16 + r;
                #pragma unroll
                for (int q = 0; q < 4; ++q) {
                    float v = fmaxf(rg ? acc1[f][q] : acc0[f][q], 0.0f);
                    size_t idx = (size_t)(base + kq * 4 + q) * DH + col;
                    unsigned short h = f2bf_rne(v);   // RNE: gather2 reads hi only
                    Hhi[idx] = h;
                    Hlo[idx] = f2bf_rne(v - bf2f(h));
                }
            }
        }
    } else {
        float wo[8];
        #pragma unroll
        for (int f = 0; f < 8; ++f) wo[f] = Wo[f * 16 + r];
        #pragma unroll
        for (int rg = 0; rg < 2; ++rg) {
            if (rg == 1 && !v1) break;
            int base = rg ? base1 : base0;
            float s[4] = {0.f, 0.f, 0.f, 0.f};
            #pragma unroll
            for (int f = 0; f < 8; ++f)
                #pragma unroll
                for (int q = 0; q < 4; ++q)
                    s[q] += fmaxf(rg ? acc1[f][q] : acc0[f][q], 0.0f) * wo[f];
            #pragma unroll
            for (int m = 1; m < 16; m <<= 1) {
                s[0] += __shfl_xor(s[0], m);
                s[1] += __shfl_xor(s[1], m);
                s[2] += __shfl_xor(s[2], m);
                s[3] += __shfl_xor(s[3], m);
            }
            if (r < 4) outp[base + kq * 4 + r] = s[r] + bo[0];
        }
    }
}

extern "C" void kernel_launch(void* const* d_in, const int* in_sizes, int n_in,
                              void* d_out, int out_size, void* d_ws, size_t ws_size,
                              hipStream_t stream) {
    const float* x   = (const float*)d_in[0];
    const int*   ei  = (const int*)d_in[1];
    const float* W1l = (const float*)d_in[2];
    const float* b1  = (const float*)d_in[3];
    const float* W1r = (const float*)d_in[4];
    const float* W2l = (const float*)d_in[5];
    const float* b2  = (const float*)d_in[6];
    const float* W2r = (const float*)d_in[7];
    const float* Wo  = (const float*)d_in[8];
    const float* bo  = (const float*)d_in[9];
    float* out = (float*)d_out;

    const int N = in_sizes[0] / DH;      // 40000
    const int E = in_sizes[1] / 2;       // 640000
    const int* src = ei;
    const int* dst = ei + E;
    const int nb = (N + 255) / 256;      // scan1 blocks (<=256)
    const size_t NDH = (size_t)N * DH;
    const int n4 = N * DH / 4;
    const int nbA = (n4 + 255) / 256;    // tobf blocks
    const int nbB = (E + 255) / 256;     // deg blocks

    // workspace layout
    unsigned short* xhi   = (unsigned short*)d_ws;   // N*128 each
    unsigned short* xlo   = xhi + NDH;
    unsigned short* h1hi  = xlo + NDH;
    unsigned short* h1lo  = h1hi + NDH;
    unsigned short* agghi = h1lo + NDH;
    unsigned short* agglo = agghi + NDH;
    unsigned short* whi   = agglo + NDH;             // 2*32768
    unsigned short* wlo   = whi + 65536;             // 2*32768
    int* deg    = (int*)(wlo + 65536);               // N
    int* cursor = deg + N;                           // N (adjacent: one memset)
    int* offs   = cursor + N;                        // N
    int* bsum   = offs + N;                          // 256
    int* boffs  = bsum + 256;                        // 256
    int* csr    = boffs + 256;                       // E

    // ---- prep + CSR build ----
    hipMemsetAsync(deg, 0, 2 * (size_t)N * sizeof(int), stream);
    prep_kernel<<<nbA + nbB + 32, 256, 0, stream>>>(
        x, xhi, xlo, dst, deg, W1l, W1r, W2l, W2r, whi, wlo, n4, E, nbA, nbB);
    scan1_kernel<<<nb, 256, 0, stream>>>(deg, offs, bsum, N);
    scan2_kernel<<<1, 256, 0, stream>>>(bsum, boffs, nb);
    fill_kernel<<<nbB, 256, 0, stream>>>(src, dst, offs, boffs, cursor, csr, E);

    const int convGrid = (N + 127) / 128;

    // ---- layer 1 ----
    gather_mean_kernel<<<(N + 3) / 4, 256, 0, stream>>>(
        xhi, csr, offs, boffs, deg, agghi, agglo, N);
    sage_mfma_kernel<0><<<convGrid, 256, 0, stream>>>(
        agghi, agglo, xhi, xlo, whi, wlo, b1, h1hi, h1lo,
        nullptr, nullptr, nullptr, N);

    // ---- layer 2 + head ----
    gather_mean_kernel<<<(N + 3) / 4, 256, 0, stream>>>(
        h1hi, csr, offs, boffs, deg, agghi, agglo, N);
    sage_mfma_kernel<1><<<convGrid, 256, 0, stream>>>(
        agghi, agglo, h1hi, h1lo, whi + 32768, wlo + 32768, b2, nullptr, nullptr,
        Wo, bo, out, N);
}

// Round 7
// 244.533 us; speedup vs baseline: 1.2702x; 1.0549x over previous
//
#include <hip/hip_runtime.h>
#include <hip/hip_bf16.h>

// GraphSAGE: 2x SAGEConv(mean) + linear head. N=40000, E=640000, D=128.
// Round 7: (a) padded CSR (96 slots/node) -> no scans, histogram+fill fused
// into prep; chain is 6 dispatches. (b) gather restructured: 8 edge-slots x
// 8 row-chunks per wave, 16B uint4 loads, 2-deep unroll -> 32 outstanding
// 16B loads/wave (was 8x8B) to hide L2-miss/L3 latency. Convs unchanged
// (bf16x3 MFMA, pre-split operands, head fused into conv2).

#define DH 128
#define CAP 96

typedef __attribute__((ext_vector_type(8))) short bf16x8;
typedef __attribute__((ext_vector_type(4))) float f32x4;

__device__ __forceinline__ unsigned short f2bf_rne(float f) {
    unsigned int u = __float_as_uint(f);
    return (unsigned short)((u + 0x7FFFu + ((u >> 16) & 1u)) >> 16);
}
__device__ __forceinline__ float bf2f(unsigned short h) {
    return __uint_as_float(((unsigned int)h) << 16);
}
__device__ __forceinline__ float bflo(unsigned int u) {
    return __uint_as_float(u << 16);
}
__device__ __forceinline__ float bfhi(unsigned int u) {
    return __uint_as_float(u & 0xffff0000u);
}
// pack two fp32 into one u32 of 2 bf16: hi=truncation, lo=RNE(remainder)
__device__ __forceinline__ unsigned packpair_hi(float a, float b) {
    return (__float_as_uint(b) & 0xffff0000u) | (__float_as_uint(a) >> 16);
}
__device__ __forceinline__ unsigned packpair_lo(float a, float b) {
    float ra = a - bfhi(__float_as_uint(a));
    float rb = b - bfhi(__float_as_uint(b));
    return ((unsigned)f2bf_rne(rb) << 16) | f2bf_rne(ra);
}

// ---------------- fused prep ----------------
// Roles: [0,nbA): x -> bf16 hi/lo rows (hi RNE: gather1 consumes hi alone).
//        [nbA,nbA+nbB): padded-CSR fill (histogram + slot write in one pass).
//        [nbA+nbB,+32): W fragment pre-split (bf16 hi/lo, MFMA layout).

__global__ __launch_bounds__(256) void prep_kernel(
    const float* __restrict__ x,
    unsigned short* __restrict__ xhi, unsigned short* __restrict__ xlo,
    const int* __restrict__ src, const int* __restrict__ dst,
    int* __restrict__ cursor, int* __restrict__ csr,
    const float* __restrict__ W1l, const float* __restrict__ W1r,
    const float* __restrict__ W2l, const float* __restrict__ W2r,
    unsigned short* __restrict__ whi, unsigned short* __restrict__ wlo,
    int n4, int E, int nbA, int nbB)
{
    int b = blockIdx.x;
    if (b < nbA) {
        int i = b * 256 + threadIdx.x;
        if (i >= n4) return;
        float4 v = ((const float4*)x)[i];
        unsigned short hx = f2bf_rne(v.x), hy = f2bf_rne(v.y);
        unsigned short hz = f2bf_rne(v.z), hw = f2bf_rne(v.w);
        uint2 hi, lo;
        hi.x = ((unsigned)hy << 16) | hx;
        hi.y = ((unsigned)hw << 16) | hz;
        lo.x = ((unsigned)f2bf_rne(v.y - bf2f(hy)) << 16) | f2bf_rne(v.x - bf2f(hx));
        lo.y = ((unsigned)f2bf_rne(v.w - bf2f(hw)) << 16) | f2bf_rne(v.z - bf2f(hz));
        ((uint2*)xhi)[i] = hi;
        ((uint2*)xlo)[i] = lo;
    } else if (b < nbA + nbB) {
        int e = (b - nbA) * 256 + threadIdx.x;
        if (e >= E) return;
        int d = dst[e];
        int pos = atomicAdd(&cursor[d], 1);
        if (pos < CAP) csr[(size_t)d * CAP + pos] = src[e];
    } else {
        int tid = (b - nbA - nbB) * 256 + threadIdx.x;  // [conv][t][f][lane]
        if (tid >= 2 * 8 * 8 * 64) return;
        int lane = tid & 63;
        int f = (tid >> 6) & 7;
        int t = (tid >> 9) & 7;
        int conv = tid >> 12;
        const float* Wl = conv ? W2l : W1l;
        const float* Wr = conv ? W2r : W1r;
        int c = f * 16 + (lane & 15);
        int kb = t * 32 + (lane >> 4) * 8;
        size_t off = (size_t)tid * 8;
        #pragma unroll
        for (int j = 0; j < 8; ++j) {
            int k = kb + j;
            float w = (k < 128) ? Wl[k * 128 + c] : Wr[(k - 128) * 128 + c];
            unsigned short h = f2bf_rne(w);
            whi[off + j] = h;
            wlo[off + j] = f2bf_rne(w - bf2f(h));
        }
    }
}

// ------------- gather mean (one wave per node, 8 slots x 8 chunks) ---------
// lane = slot*8 + ch. Edge slot handles every 8th edge; chunk ch covers
// elems [ch*16, ch*16+16) = 32B = 2 x uint4 loads. 2-deep unroll -> up to
// 32 outstanding 16B loads per wave. Slot-reduce via 3 shfl_xor steps.
// Output: bf16 hi(trunc)/lo(RNE remainder) pair (conv consumes the pair).

__global__ __launch_bounds__(256) void gather_mean_kernel(
    const unsigned short* __restrict__ featbf, const int* __restrict__ csr,
    const int* __restrict__ deg,
    unsigned short* __restrict__ outhi, unsigned short* __restrict__ outlo, int N)
{
    int node = blockIdx.x * 4 + (threadIdx.x >> 6);
    if (node >= N) return;
    const int lane = threadIdx.x & 63;
    const int ch = lane & 7;
    const int slot = lane >> 3;

    const int dg = min(deg[node], CAP);
    const int* row = csr + (size_t)node * CAP;

    float a[16], b[16];
    #pragma unroll
    for (int i = 0; i < 16; ++i) { a[i] = 0.f; b[i] = 0.f; }

    int e = slot;
    for (; e + 8 < dg; e += 16) {
        int s0 = row[e];
        int s1 = row[e + 8];
        const uint4* p0 = (const uint4*)&featbf[(size_t)s0 * DH + ch * 16];
        const uint4* p1 = (const uint4*)&featbf[(size_t)s1 * DH + ch * 16];
        uint4 v0 = p0[0], w0 = p0[1];
        uint4 v1 = p1[0], w1 = p1[1];
        a[0] += bflo(v0.x); a[1] += bfhi(v0.x); a[2] += bflo(v0.y); a[3] += bfhi(v0.y);
        a[4] += bflo(v0.z); a[5] += bfhi(v0.z); a[6] += bflo(v0.w); a[7] += bfhi(v0.w);
        a[8] += bflo(w0.x); a[9] += bfhi(w0.x); a[10]+= bflo(w0.y); a[11]+= bfhi(w0.y);
        a[12]+= bflo(w0.z); a[13]+= bfhi(w0.z); a[14]+= bflo(w0.w); a[15]+= bfhi(w0.w);
        b[0] += bflo(v1.x); b[1] += bfhi(v1.x); b[2] += bflo(v1.y); b[3] += bfhi(v1.y);
        b[4] += bflo(v1.z); b[5] += bfhi(v1.z); b[6] += bflo(v1.w); b[7] += bfhi(v1.w);
        b[8] += bflo(w1.x); b[9] += bfhi(w1.x); b[10]+= bflo(w1.y); b[11]+= bfhi(w1.y);
        b[12]+= bflo(w1.z); b[13]+= bfhi(w1.z); b[14]+= bflo(w1.w); b[15]+= bfhi(w1.w);
    }
    if (e < dg) {
        int s0 = row[e];
        const uint4* p0 = (const uint4*)&featbf[(size_t)s0 * DH + ch * 16];
        uint4 v0 = p0[0], w0 = p0[1];
        a[0] += bflo(v0.x); a[1] += bfhi(v0.x); a[2] += bflo(v0.y); a[3] += bfhi(v0.y);
        a[4] += bflo(v0.z); a[5] += bfhi(v0.z); a[6] += bflo(v0.w); a[7] += bfhi(v0.w);
        a[8] += bflo(w0.x); a[9] += bfhi(w0.x); a[10]+= bflo(w0.y); a[11]+= bfhi(w0.y);
        a[12]+= bflo(w0.z); a[13]+= bfhi(w0.z); a[14]+= bflo(w0.w); a[15]+= bfhi(w0.w);
    }
    #pragma unroll
    for (int i = 0; i < 16; ++i) a[i] += b[i];
    #pragma unroll
    for (int m = 8; m < 64; m <<= 1)
        #pragma unroll
        for (int i = 0; i < 16; ++i)
            a[i] += __shfl_xor(a[i], m);

    if (slot == 0) {
        float sc = 1.0f / (float)max(dg, 1);
        #pragma unroll
        for (int i = 0; i < 16; ++i) a[i] *= sc;
        uint4 hi0, hi1, lo0, lo1;
        hi0.x = packpair_hi(a[0], a[1]);   lo0.x = packpair_lo(a[0], a[1]);
        hi0.y = packpair_hi(a[2], a[3]);   lo0.y = packpair_lo(a[2], a[3]);
        hi0.z = packpair_hi(a[4], a[5]);   lo0.z = packpair_lo(a[4], a[5]);
        hi0.w = packpair_hi(a[6], a[7]);   lo0.w = packpair_lo(a[6], a[7]);
        hi1.x = packpair_hi(a[8], a[9]);   lo1.x = packpair_lo(a[8], a[9]);
        hi1.y = packpair_hi(a[10], a[11]); lo1.y = packpair_lo(a[10], a[11]);
        hi1.z = packpair_hi(a[12], a[13]); lo1.z = packpair_lo(a[12], a[13]);
        hi1.w = packpair_hi(a[14], a[15]); lo1.w = packpair_lo(a[14], a[15]);
        uint4* ph = (uint4*)&outhi[(size_t)node * DH + ch * 16];
        uint4* pl = (uint4*)&outlo[(size_t)node * DH + ch * 16];
        ph[0] = hi0; ph[1] = hi1;
        pl[0] = lo0; pl[1] = lo1;
    }
}

// ---------------- SAGE conv via bf16x3 MFMA, pre-split operands --------------
// HEAD==0: relu([Agg|X]@[Wl;Wr]+b) -> Hhi (RNE bf16, gather2 input) + Hlo.
// HEAD==1: out = relu(...)@Wo + bo (16-lane shfl_xor reduce).
// 4 waves/block, 32 rows/wave (2 row-groups 64 apart), no LDS, no barriers.

template<int HEAD>
__global__ __launch_bounds__(256) void sage_mfma_kernel(
    const unsigned short* __restrict__ agghi, const unsigned short* __restrict__ agglo,
    const unsigned short* __restrict__ xhi, const unsigned short* __restrict__ xlo,
    const unsigned short* __restrict__ whi, const unsigned short* __restrict__ wlo,
    const float* __restrict__ bias,
    unsigned short* __restrict__ Hhi, unsigned short* __restrict__ Hlo,
    const float* __restrict__ Wo, const float* __restrict__ bo,
    float* __restrict__ outp, int N)
{
    const int l = threadIdx.x & 63;
    const int wv = threadIdx.x >> 6;
    const int r = l & 15;
    const int kq = l >> 4;
    const int base0 = blockIdx.x * 128 + wv * 16;
    const int base1 = base0 + 64;
    const bool v1 = (base1 + 16 <= N);

    f32x4 acc0[8], acc1[8];
    #pragma unroll
    for (int f = 0; f < 8; ++f) {
        float b = bias[f * 16 + r];
        acc0[f] = (f32x4){b, b, b, b};
        acc1[f] = (f32x4){b, b, b, b};
    }

    #pragma unroll
    for (int t = 0; t < 8; ++t) {
        const unsigned short* Ah = (t < 4) ? agghi : xhi;
        const unsigned short* Al = (t < 4) ? agglo : xlo;
        size_t ao0 = (size_t)(base0 + r) * DH + (t & 3) * 32 + kq * 8;
        bf16x8 a0h = *(const bf16x8*)&Ah[ao0];
        bf16x8 a0l = *(const bf16x8*)&Al[ao0];
        bf16x8 a1h = {0,0,0,0,0,0,0,0};
        bf16x8 a1l = {0,0,0,0,0,0,0,0};
        if (v1) {
            size_t ao1 = ao0 + (size_t)64 * DH;
            a1h = *(const bf16x8*)&Ah[ao1];
            a1l = *(const bf16x8*)&Al[ao1];
        }
        const unsigned short* bh = whi + ((size_t)(t * 8) * 64 + l) * 8;
        const unsigned short* bl = wlo + ((size_t)(t * 8) * 64 + l) * 8;
        #pragma unroll
        for (int f = 0; f < 8; ++f) {
            bf16x8 bhi = *(const bf16x8*)(bh + (size_t)f * 512);
            bf16x8 blo = *(const bf16x8*)(bl + (size_t)f * 512);
            acc0[f] = __builtin_amdgcn_mfma_f32_16x16x32_bf16(a0h, bhi, acc0[f], 0, 0, 0);
            acc0[f] = __builtin_amdgcn_mfma_f32_16x16x32_bf16(a0l, bhi, acc0[f], 0, 0, 0);
            acc0[f] = __builtin_amdgcn_mfma_f32_16x16x32_bf16(a0h, blo, acc0[f], 0, 0, 0);
            acc1[f] = __builtin_amdgcn_mfma_f32_16x16x32_bf16(a1h, bhi, acc1[f], 0, 0, 0);
            acc1[f] = __builtin_amdgcn_mfma_f32_16x16x32_bf16(a1l, bhi, acc1[f], 0, 0, 0);
            acc1[f] = __builtin_amdgcn_mfma_f32_16x16x32_bf16(a1h, blo, acc1[f], 0, 0, 0);
        }
    }

    if (HEAD == 0) {
        #pragma unroll
        for (int rg = 0; rg < 2; ++rg) {
            if (rg == 1 && !v1) break;
            int base = rg ? base1 : base0;
            #pragma unroll
            for (int f = 0; f < 8; ++f) {
                int col = f * 16 + r;
                #pragma unroll
                for (int q = 0; q < 4; ++q) {
                    float v = fmaxf(rg ? acc1[f][q] : acc0[f][q], 0.0f);
                    size_t idx = (size_t)(base + kq * 4 + q) * DH + col;
                    unsigned short h = f2bf_rne(v);   // RNE: gather2 reads hi only
                    Hhi[idx] = h;
                    Hlo[idx] = f2bf_rne(v - bf2f(h));
                }
            }
        }
    } else {
        float wo[8];
        #pragma unroll
        for (int f = 0; f < 8; ++f) wo[f] = Wo[f * 16 + r];
        #pragma unroll
        for (int rg = 0; rg < 2; ++rg) {
            if (rg == 1 && !v1) break;
            int base = rg ? base1 : base0;
            float s[4] = {0.f, 0.f, 0.f, 0.f};
            #pragma unroll
            for (int f = 0; f < 8; ++f)
                #pragma unroll
                for (int q = 0; q < 4; ++q)
                    s[q] += fmaxf(rg ? acc1[f][q] : acc0[f][q], 0.0f) * wo[f];
            #pragma unroll
            for (int m = 1; m < 16; m <<= 1) {
                s[0] += __shfl_xor(s[0], m);
                s[1] += __shfl_xor(s[1], m);
                s[2] += __shfl_xor(s[2], m);
                s[3] += __shfl_xor(s[3], m);
            }
            if (r < 4) outp[base + kq * 4 + r] = s[r] + bo[0];
        }
    }
}

extern "C" void kernel_launch(void* const* d_in, const int* in_sizes, int n_in,
                              void* d_out, int out_size, void* d_ws, size_t ws_size,
                              hipStream_t stream) {
    const float* x   = (const float*)d_in[0];
    const int*   ei  = (const int*)d_in[1];
    const float* W1l = (const float*)d_in[2];
    const float* b1  = (const float*)d_in[3];
    const float* W1r = (const float*)d_in[4];
    const float* W2l = (const float*)d_in[5];
    const float* b2  = (const float*)d_in[6];
    const float* W2r = (const float*)d_in[7];
    const float* Wo  = (const float*)d_in[8];
    const float* bo  = (const float*)d_in[9];
    float* out = (float*)d_out;

    const int N = in_sizes[0] / DH;      // 40000
    const int E = in_sizes[1] / 2;       // 640000
    const int* src = ei;
    const int* dst = ei + E;
    const size_t NDH = (size_t)N * DH;
    const int n4 = N * DH / 4;
    const int nbA = (n4 + 255) / 256;    // x-split blocks
    const int nbB = (E + 255) / 256;     // fill blocks

    // workspace layout
    unsigned short* xhi   = (unsigned short*)d_ws;   // N*128 each
    unsigned short* xlo   = xhi + NDH;
    unsigned short* h1hi  = xlo + NDH;
    unsigned short* h1lo  = h1hi + NDH;
    unsigned short* agghi = h1lo + NDH;
    unsigned short* agglo = agghi + NDH;
    unsigned short* whi   = agglo + NDH;             // 2*32768
    unsigned short* wlo   = whi + 65536;             // 2*32768
    int* cursor = (int*)(wlo + 65536);               // N (doubles as deg)
    int* csr    = cursor + N;                        // N*CAP

    // ---- prep: x-split + padded-CSR fill + W-split (one kernel) ----
    hipMemsetAsync(cursor, 0, (size_t)N * sizeof(int), stream);
    prep_kernel<<<nbA + nbB + 32, 256, 0, stream>>>(
        x, xhi, xlo, src, dst, cursor, csr,
        W1l, W1r, W2l, W2r, whi, wlo, n4, E, nbA, nbB);

    const int convGrid = (N + 127) / 128;

    // ---- layer 1 ----
    gather_mean_kernel<<<(N + 3) / 4, 256, 0, stream>>>(
        xhi, csr, cursor, agghi, agglo, N);
    sage_mfma_kernel<0><<<convGrid, 256, 0, stream>>>(
        agghi, agglo, xhi, xlo, whi, wlo, b1, h1hi, h1lo,
        nullptr, nullptr, nullptr, N);

    // ---- layer 2 + head ----
    gather_mean_kernel<<<(N + 3) / 4, 256, 0, stream>>>(
        h1hi, csr, cursor, agghi, agglo, N);
    sage_mfma_kernel<1><<<convGrid, 256, 0, stream>>>(
        agghi, agglo, h1hi, h1lo, whi + 32768, wlo + 32768, b2, nullptr, nullptr,
        Wo, bo, out, N);
}